// Round 5
// baseline (246.380 us; speedup 1.0000x reference)
//
#include <hip/hip_runtime.h>
#include <hip/hip_bf16.h>

#define TOKENS 4096
#define IN_F   4096
#define OUT_F  4096

typedef __bf16 bf16x8 __attribute__((ext_vector_type(8)));
typedef float  f32x4  __attribute__((ext_vector_type(4)));
typedef unsigned int u32;
typedef u32 u32x4 __attribute__((ext_vector_type(4)));

#define DEQ_BLOCKS 2048   // 4096 rows * 128 thread-chunks / 256
#define CVT_BLOCKS 4096   // 4096*4096 /16 /256

__device__ __forceinline__ void gld_lds16(const void* g, void* l) {
    __builtin_amdgcn_global_load_lds(
        (const __attribute__((address_space(1))) u32*)g,
        (__attribute__((address_space(3))) u32*)l,
        16, 0, 0);
}

// ---------------------------------------------------------------------------
// Fused prep (unchanged from verified 255us version)
// ---------------------------------------------------------------------------
__global__ __launch_bounds__(256) void prep_kernel(
        const u32* __restrict__ qweight, const u32* __restrict__ qzeros,
        const float* __restrict__ scales, const float* __restrict__ x,
        __bf16* __restrict__ W, __bf16* __restrict__ A) {
    const int tid = threadIdx.x;
    if (blockIdx.x < DEQ_BLOCKS) {
        int idx4 = blockIdx.x * 256 + tid;      // 0 .. 524287
        int n  = idx4 >> 7;                     // out row (128 chunks/row)
        int p4 = (idx4 & 127) << 2;             // first packed col (0..508)
        int g  = p4 >> 4;                       // group id (constant over 4)
        u32 qz = qzeros[(n << 2) + (g >> 3)];
        float z = (float)((qz >> ((g & 7) * 4)) & 15);
        float s = scales[(n << 5) + g];
        u32x4 qw = *(const u32x4*)(qweight + (size_t)n * 512 + p4);
        __bf16* dst = W + (size_t)n * IN_F + p4 * 8;
#pragma unroll
        for (int c = 0; c < 4; ++c) {
            bf16x8 h;
#pragma unroll
            for (int j = 0; j < 8; ++j) {
                float w = ((float)((qw[c] >> (4 * j)) & 15) - z) * s;
                h[j] = (__bf16)w;
            }
            *(bf16x8*)(dst + c * 8) = h;
        }
    } else {
        int idx = (blockIdx.x - DEQ_BLOCKS) * 256 + tid;   // 0 .. 1048575
        const f32x4* xp = (const f32x4*)x + (size_t)idx * 4;
        f32x4 v0 = xp[0], v1 = xp[1], v2 = xp[2], v3 = xp[3];
        bf16x8 h0, h1;
#pragma unroll
        for (int j = 0; j < 4; ++j) {
            h0[j] = (__bf16)v0[j]; h0[4 + j] = (__bf16)v1[j];
            h1[j] = (__bf16)v2[j]; h1[4 + j] = (__bf16)v3[j];
        }
        bf16x8* ap = (bf16x8*)A + (size_t)idx * 2;
        ap[0] = h0; ap[1] = h1;
    }
}

// ---------------------------------------------------------------------------
// 256x256 GEMM, round 5: double-buffered fragment registers + EARLY read
// injection. Round-4 left ~300 cyc/phase of exposed ds_read latency (tail
// reads issued at burst end, drained immediately after the barrier). Now
// af0/af1 and bf0/bf1 rotate so every next-phase read is injected in the
// first half of the burst (~300+ cyc to complete before the barrier).
//   Rotation (tile t, buf B):
//     P0 mfma{af0=pm0kh0, bf0=kh0}  inject af1<-pm1kh0(B), bf1<-kh1(B)
//     P1 mfma{af1,        bf0}      inject af0<-pm0kh1(B)
//     P2 mfma{af0,        bf1=kh1}  inject af1<-pm1kh1(B), bf0<-kh0(t+1)
//     P3 mfma{af1,        bf1}      inject af0<-pm0kh0(t+1)
//   STAGE (unchanged): P0->(t+1).Ah1  P1->(t+1).Bh1  P2->(t+2).Ah0
//   P3->(t+2).Bh0.  Waits now at PHASE OPEN (after STAGE):
//     P2 VM6: outstanding [(t+1)Ah0,Bh0,Ah1,Bh1,(t+2)Ah0]=10 -> completes
//       (t+1)Ah0/Bh0 (issued 3-4 phases prior, > HBM latency; read by
//       P2's bf0 injection and P3's af0 injection).
//     P3 VM4: outstanding [(t+1)Ah1,Bh1,(t+2)Ah0,Bh0]=8 -> completes
//       (t+1)Ah1/Bh1 (read by (t+1).P0 bf1 / (t+1).P1 af0 injections).
//   FIFO-simulated over t=0,1,2: invariant holds cyclically.
//   WAR (reads in p vs STAGE in p+1..): every region's last read is >=1
//   full phase (with lgkmcnt(0) drain at p+1 open) before its re-STAGE;
//   cross-wave margin: ds_read serviced ~100cyc, overwrite arrives
//   >=900cyc (HBM) after next-phase issue.
// ---------------------------------------------------------------------------
__global__ __launch_bounds__(512, 2) void gemm8p(
        const __bf16* __restrict__ A, const __bf16* __restrict__ B,
        const float* __restrict__ bias, float* __restrict__ C) {
    __shared__ __align__(16) char lsA[65536];
    __shared__ __align__(16) char lsB[65536];

    const int t    = threadIdx.x;
    const int lane = t & 63, wave = t >> 6;
    const int lr   = lane & 15, quad = lane >> 4;
    const int wm   = (wave >> 2) * 128;   // 2 M groups
    const int wn   = (wave & 3) * 64;     // 4 N groups

    // XCD-aware swizzle: 256 blocks, 8 XCDs, 32 contiguous tiles per XCD
    int bid = blockIdx.x;
    bid = (bid & 7) * 32 + (bid >> 3);
    const int bm = bid >> 4, bn = bid & 15;

    const __bf16* Abase = A + (size_t)bm * 256 * IN_F;
    const __bf16* Bbase = B + (size_t)bn * 256 * IN_F;

    // staging: linear LDS dest, pre-swizzled global source (rule #21)
    const int srow0 = t >> 2;               // rows 0..127
    const int srow1 = 128 + (t >> 2);       // rows 128..255
    const int scol0 = ((t & 3) ^ ((srow0 >> 1) & 3)) * 8;   // elements
    const int scol1 = ((t & 3) ^ ((srow1 >> 1) & 3)) * 8;

#define STAGE(OPBASE, LS, KT, KH, BUF) do {                                  \
    int _kb = (((KT) & 63) * 64 + (KH) * 32);                                \
    gld_lds16(OPBASE + (size_t)srow0 * IN_F + _kb + scol0,                   \
              LS + ((BUF) * 2 + (KH)) * 16384 + t * 16);                     \
    gld_lds16(OPBASE + (size_t)srow1 * IN_F + _kb + scol1,                   \
              LS + ((BUF) * 2 + (KH)) * 16384 + 8192 + t * 16);              \
} while (0)

    // LDS byte bases for asm ds_read; read slot = quad ^ ((lr>>1)&3)
    const u32 slot16 = (u32)((quad ^ ((lr >> 1) & 3)) * 16);
    const u32 lsA0 = (u32)(size_t)(__attribute__((address_space(3))) char*)lsA;
    const u32 lsB0 = (u32)(size_t)(__attribute__((address_space(3))) char*)lsB;
    const u32 aA = lsA0 + (u32)((wm + lr) * 64) + slot16;
    const u32 aB = lsB0 + (u32)((wn + lr) * 64) + slot16;

    bf16x8 af0[4], af1[4], bf0[4], bf1[4];
    f32x4 acc[8][4] = {};

// region byte offsets within lsA/lsB: [buf][kh] x 16 KiB; pm adds 4096
#define RA(BUF, KH) (((BUF) * 2 + (KH)) * 16384)
#define RB(BUF, KH) (((BUF) * 2 + (KH)) * 16384)

// inline-asm ds_read_b128 (opaque to waitcnt pass; manual lgkm discipline)
#define DSR(dst, base, OFF) do {                                             \
    u32x4 _r;                                                                \
    asm volatile("ds_read_b128 %0, %1 offset:%2"                             \
                 : "=v"(_r) : "v"(base), "n"(OFF));                          \
    dst = __builtin_bit_cast(bf16x8, _r);                                    \
} while (0)

// one MFMA group: 4 MFMAs, row-tile I of half-tile PM, frag sets AF/BF
#define G4(PM, I, AF, BF) do {                                               \
    _Pragma("unroll")                                                        \
    for (int j = 0; j < 4; ++j)                                              \
        acc[(PM) * 4 + (I)][j] = __builtin_amdgcn_mfma_f32_16x16x32_bf16(    \
            AF[(I)], BF[j], acc[(PM) * 4 + (I)][j], 0, 0, 0);                \
} while (0)

#define FENCE() asm volatile("" ::: "memory")
#define BAR()  do { FENCE(); __builtin_amdgcn_s_barrier(); FENCE(); } while (0)
#define VM6()  asm volatile("s_waitcnt vmcnt(6)" ::: "memory")
#define VM4()  asm volatile("s_waitcnt vmcnt(4)" ::: "memory")
#define PRIO(x) __builtin_amdgcn_s_setprio(x)
#define SB()   __builtin_amdgcn_sched_barrier(0)
#define LGKM0SB() do {                                                       \
    asm volatile("s_waitcnt lgkmcnt(0)" ::: "memory"); SB(); } while (0)

// P0: mfma{af0,bf0}; inject af1<-pm1kh0(B), bf1<-kh1(B)  (2 reads/group)
#define P0_BODY(KT, B) do {                                                  \
    STAGE(Abase, lsA, (KT) + 1, 1, 1 - (B));                                 \
    LGKM0SB(); PRIO(1);                                                      \
    G4(0,0,af0,bf0); SB(); DSR(af1[0], aA, RA(B,0)+4096+0*1024);             \
                           DSR(bf1[0], aB, RB(B,1)+0*1024); SB();            \
    G4(0,1,af0,bf0); SB(); DSR(af1[1], aA, RA(B,0)+4096+1*1024);             \
                           DSR(bf1[1], aB, RB(B,1)+1*1024); SB();            \
    G4(0,2,af0,bf0); SB(); DSR(af1[2], aA, RA(B,0)+4096+2*1024);             \
                           DSR(bf1[2], aB, RB(B,1)+2*1024); SB();            \
    G4(0,3,af0,bf0); SB(); DSR(af1[3], aA, RA(B,0)+4096+3*1024);             \
                           DSR(bf1[3], aB, RB(B,1)+3*1024); SB();            \
    PRIO(0); BAR();                                                          \
} while (0)

// P1: mfma{af1,bf0}; inject af0<-pm0kh1(B)  (1 read/group)
#define P1_BODY(KT, B) do {                                                  \
    STAGE(Bbase, lsB, (KT) + 1, 1, 1 - (B));                                 \
    LGKM0SB(); PRIO(1);                                                      \
    G4(1,0,af1,bf0); SB(); DSR(af0[0], aA, RA(B,1)+0*1024); SB();            \
    G4(1,1,af1,bf0); SB(); DSR(af0[1], aA, RA(B,1)+1*1024); SB();            \
    G4(1,2,af1,bf0); SB(); DSR(af0[2], aA, RA(B,1)+2*1024); SB();            \
    G4(1,3,af1,bf0); SB(); DSR(af0[3], aA, RA(B,1)+3*1024); SB();            \
    PRIO(0); BAR();                                                          \
} while (0)

// P2: mfma{af0,bf1}; VM6 at open; inject af1<-pm1kh1(B), bf0<-kh0(1-B)
#define P2_BODY(KT, B) do {                                                  \
    STAGE(Abase, lsA, (KT) + 2, 0, (B));                                     \
    VM6(); LGKM0SB(); PRIO(1);                                               \
    G4(0,0,af0,bf1); SB(); DSR(af1[0], aA, RA(B,1)+4096+0*1024);             \
                           DSR(bf0[0], aB, RB(1-(B),0)+0*1024); SB();        \
    G4(0,1,af0,bf1); SB(); DSR(af1[1], aA, RA(B,1)+4096+1*1024);             \
                           DSR(bf0[1], aB, RB(1-(B),0)+1*1024); SB();        \
    G4(0,2,af0,bf1); SB(); DSR(af1[2], aA, RA(B,1)+4096+2*1024);             \
                           DSR(bf0[2], aB, RB(1-(B),0)+2*1024); SB();        \
    G4(0,3,af0,bf1); SB(); DSR(af1[3], aA, RA(B,1)+4096+3*1024);             \
                           DSR(bf0[3], aB, RB(1-(B),0)+3*1024); SB();        \
    PRIO(0); BAR();                                                          \
} while (0)

// P3: mfma{af1,bf1}; VM4 at open; inject af0<-pm0kh0(1-B)
#define P3_BODY(KT, B) do {                                                  \
    STAGE(Bbase, lsB, (KT) + 2, 0, (B));                                     \
    VM4(); LGKM0SB(); PRIO(1);                                               \
    G4(1,0,af1,bf1); SB(); DSR(af0[0], aA, RA(1-(B),0)+0*1024); SB();        \
    G4(1,1,af1,bf1); SB(); DSR(af0[1], aA, RA(1-(B),0)+1*1024); SB();        \
    G4(1,2,af1,bf1); SB(); DSR(af0[2], aA, RA(1-(B),0)+2*1024); SB();        \
    G4(1,3,af1,bf1); SB(); DSR(af0[3], aA, RA(1-(B),0)+3*1024); SB();        \
    PRIO(0); BAR();                                                          \
} while (0)

    // prologue: stage tile0 fully + tile1 kh0 (12 loads);
    // vmcnt(4) completes all of tile0, leaves tile1.kh0 in flight.
    STAGE(Abase, lsA, 0, 0, 0);
    STAGE(Bbase, lsB, 0, 0, 0);
    STAGE(Abase, lsA, 0, 1, 0);
    STAGE(Bbase, lsB, 0, 1, 0);
    STAGE(Abase, lsA, 1, 0, 1);
    STAGE(Bbase, lsB, 1, 0, 1);
    VM4();
    BAR();
    // preload frags for 0.P0: af0 = pm0 kh0 buf0, bf0 = kh0 buf0
    DSR(bf0[0], aB, RB(0,0)+0*1024); DSR(bf0[1], aB, RB(0,0)+1*1024);
    DSR(bf0[2], aB, RB(0,0)+2*1024); DSR(bf0[3], aB, RB(0,0)+3*1024);
    DSR(af0[0], aA, RA(0,0)+0*1024); DSR(af0[1], aA, RA(0,0)+1*1024);
    DSR(af0[2], aA, RA(0,0)+2*1024); DSR(af0[3], aA, RA(0,0)+3*1024);

    for (int kt = 0; kt < 64; kt += 2) {
        P0_BODY(kt, 0); P1_BODY(kt, 0); P2_BODY(kt, 0); P3_BODY(kt, 0);
        P0_BODY(kt + 1, 1); P1_BODY(kt + 1, 1);
        P2_BODY(kt + 1, 1); P3_BODY(kt + 1, 1);
    }

    asm volatile("s_waitcnt vmcnt(0) lgkmcnt(0)" ::: "memory");

    // epilogue: C/D layout col = lane&15, row = (lane>>4)*4 + reg
    const int row0 = bm * 256 + wm + quad * 4;
    const int col0 = bn * 256 + wn + lr;
#pragma unroll
    for (int j = 0; j < 4; ++j) {
        const int col = col0 + j * 16;
        const float bv = bias[col];
#pragma unroll
        for (int i = 0; i < 8; ++i) {
            const int row = row0 + i * 16;
#pragma unroll
            for (int r = 0; r < 4; ++r)
                C[(size_t)(row + r) * OUT_F + col] = acc[i][j][r] + bv;
        }
    }
}

extern "C" void kernel_launch(void* const* d_in, const int* in_sizes, int n_in,
                              void* d_out, int out_size, void* d_ws, size_t ws_size,
                              hipStream_t stream) {
    (void)in_sizes; (void)n_in; (void)out_size; (void)ws_size;
    const float* x       = (const float*)d_in[0];
    const u32*   qweight = (const u32*)d_in[1];
    const u32*   qzeros  = (const u32*)d_in[2];
    const float* scales  = (const float*)d_in[3];
    const float* bias    = (const float*)d_in[4];
    float* out = (float*)d_out;

    __bf16* W   = (__bf16*)d_ws;                                     // 32 MB
    __bf16* Abf = (__bf16*)((char*)d_ws + (size_t)OUT_F * IN_F * 2); // 32 MB

    prep_kernel<<<dim3(DEQ_BLOCKS + CVT_BLOCKS), dim3(256), 0, stream>>>(
        qweight, qzeros, scales, x, W, Abf);
    gemm8p<<<dim3(256), dim3(512), 0, stream>>>(Abf, W, bias, out);
}

// Round 7
// 241.457 us; speedup vs baseline: 1.0204x; 1.0204x over previous
//
#include <hip/hip_runtime.h>
#include <hip/hip_bf16.h>

#define TOKENS 4096
#define IN_F   4096
#define OUT_F  4096

typedef __bf16 bf16x8 __attribute__((ext_vector_type(8)));
typedef __bf16 bf16x4 __attribute__((ext_vector_type(4)));
typedef float  f32x4  __attribute__((ext_vector_type(4)));
typedef unsigned int u32;
typedef u32 u32x4 __attribute__((ext_vector_type(4)));

#define DEQ_BLOCKS 2048   // 4096 rows * 128 threads/row
#define CVT_BLOCKS 4096   // 16.8M floats / 4096 per block

__device__ __forceinline__ void gld_lds16(const void* g, void* l) {
    __builtin_amdgcn_global_load_lds(
        (const __attribute__((address_space(1))) u32*)g,
        (__attribute__((address_space(3))) u32*)l,
        16, 0, 0);
}

// ---------------------------------------------------------------------------
// Prep: fully lane-coalesced.
//  deq: thread (n,T) handles chunks p = T + c*128 (c=0..3): qweight load
//       stride-1 dword/lane, store 16B/lane contiguous across lanes.
//  cvt: thread handles 4 f32x4 at 1024-float stride: 16B/lane loads and
//       8B/lane stores, both contiguous across lanes.
// ---------------------------------------------------------------------------
__global__ __launch_bounds__(256) void prep_kernel(
        const u32* __restrict__ qweight, const u32* __restrict__ qzeros,
        const float* __restrict__ scales, const float* __restrict__ x,
        __bf16* __restrict__ W, __bf16* __restrict__ A) {
    const int tid = threadIdx.x;
    if (blockIdx.x < DEQ_BLOCKS) {
        int idx = blockIdx.x * 256 + tid;   // 0..524287
        int n = idx >> 7;                   // out row
        int T = idx & 127;                  // chunk lane within row
        const u32* qwrow = qweight + (size_t)n * 512;
        __bf16* dst = W + (size_t)n * IN_F;
#pragma unroll
        for (int c = 0; c < 4; ++c) {
            int p = T + c * 128;            // chunk of 8 weights
            int g = p >> 4;                 // group id
            u32 qz = qzeros[(n << 2) + c];  // g>>3 == c
            float z = (float)((qz >> ((g & 7) * 4)) & 15);
            float s = scales[(n << 5) + g];
            u32 qw = qwrow[p];
            bf16x8 h;
#pragma unroll
            for (int j = 0; j < 8; ++j) {
                float w = ((float)((qw >> (4 * j)) & 15) - z) * s;
                h[j] = (__bf16)w;
            }
            *(bf16x8*)(dst + p * 8) = h;
        }
    } else {
        int b = blockIdx.x - DEQ_BLOCKS;    // 0..4095
        int base = b * 4096 + tid * 4;      // float index
#pragma unroll
        for (int k = 0; k < 4; ++k) {
            int f = base + k * 1024;
            f32x4 v = *(const f32x4*)(x + f);
            bf16x4 h;
            h[0] = (__bf16)v[0]; h[1] = (__bf16)v[1];
            h[2] = (__bf16)v[2]; h[3] = (__bf16)v[3];
            *(bf16x4*)(A + f) = h;
        }
    }
}

// ---------------------------------------------------------------------------
// 256x256 GEMM: TWO merged phases per K-tile (2 barriers/tile) + six
// fragment sets so all injected reads are early (zero tail exposure).
//   Pipe budget per tile (per CU): LDS = 96 reads*12 + 32 wr-eq*12 = 3072cyc,
//   MFMA = 512*4.85 = 2484 cyc -> LDS-bound floor ~82us.
//   LDS layout: lsA/lsB [buf][kh][8KB x2]; swizzle: slot s of row r holds
//   chunk s ^ ((r>>1)&3); read slot = quad ^ ((lr>>1)&3).
//   PhA (tile t, buf B): consume kh0 {afP0,afP1,bfE}; STAGE (t+1).h1->1-B;
//     inject afN0/afN1 <- A(B,kh1), bfO <- B(B,kh1)   [12 reads, grp 0-5]
//   PhB: consume kh1 {afN0,afN1,bfO}; STAGE (t+2).h0->B;
//     inject afP0/afP1 <- A(1-B,kh0), bfE <- B(1-B,kh0)
//   vmcnt: VM4 BEFORE each closing barrier (cross-wave visibility: a wave
//   may read a staged region only after a barrier preceded by EVERY wave's
//   vmcnt covering those loads). FIFO ledger (4 loads/phase), simulated
//   t=0,1,2 + steady state:
//     end t.PhA: outstanding [(t-1).PhB 4 = (t+1).h0, t.PhA 4 = (t+1).h1]
//       -> VM4 retires... wait applies to OLDEST: retires (t-1).PhB? No:
//       VM4 leaves 4 -> retires everything older, i.e. all loads before
//       t.PhA's 4. At that point only (t-1).PhB's 4 + t.PhA's 4 remain
//       (earlier retired by prior waits) -> retires (t-1).PhB's (t+1).h0?
//       NO: order is [(t-1).PhB(4), t.PhA(4)] -> VM4 keeps newest 4 =
//       t.PhA's -> retires (t-1).PhB's 4. Those are (t+1).h0, read first
//       by (t+1).PhA consume... and by t.PhB injections (afP0/bfE read
//       buf(1-B).kh0 = (t+1).h0's region? RA(1-B,0) staged by (t-1).PhB
//       = (t+1).h0 -> YES read by t.PhB injections, after this barrier. OK
//     end t.PhB: outstanding [t.PhA(4)=(t+1).h1, t.PhB(4)=(t+2).h0]
//       -> VM4 retires t.PhA's (t+1).h1, read by (t+1).PhA injections
//       (RA(B',1), B'=1-B) after this barrier. OK
//   WAR (stage vs last reads), each with >=1 barrier + lgkm drain between:
//     t.PhA stages (1-B,kh1): last reads = (t-1).PhA injections, drained
//       at (t-1).PhB open, barrier end-(t-1).PhA & end-(t-1).PhB precede. OK
//     t.PhB stages (B,kh0): last reads = (t-1).PhB injections, drained at
//       t.PhA open, barrier end-t.PhA precedes. OK
//   Prologue: stage t0h0,t0h1(buf0),t1h0(buf1) = 12 loads; VM4 retires
//   t0h0+t0h1; BAR; preload kh0 frags. (KT)&63 wraps OOB prefetches
//   in-bounds; garbage staged in final tiles is never consumed.
// ---------------------------------------------------------------------------
__global__ __launch_bounds__(512, 2) void gemm2p(
        const __bf16* __restrict__ A, const __bf16* __restrict__ B,
        const float* __restrict__ bias, float* __restrict__ C) {
    __shared__ __align__(16) char lsA[65536];
    __shared__ __align__(16) char lsB[65536];

    const int t    = threadIdx.x;
    const int lane = t & 63, wave = t >> 6;
    const int lr   = lane & 15, quad = lane >> 4;
    const int wm   = (wave >> 2) * 128;   // 2 M groups
    const int wn   = (wave & 3) * 64;     // 4 N groups

    // XCD-aware swizzle: 256 blocks, 8 XCDs, 32 contiguous tiles per XCD
    int bid = blockIdx.x;
    bid = (bid & 7) * 32 + (bid >> 3);
    const int bm = bid >> 4, bn = bid & 15;

    const __bf16* Abase = A + (size_t)bm * 256 * IN_F;
    const __bf16* Bbase = B + (size_t)bn * 256 * IN_F;

    // staging: linear LDS dest, pre-swizzled global source (rule #21)
    const int srow0 = t >> 2;               // rows 0..127
    const int srow1 = 128 + (t >> 2);       // rows 128..255
    const int scol0 = ((t & 3) ^ ((srow0 >> 1) & 3)) * 8;   // elements
    const int scol1 = ((t & 3) ^ ((srow1 >> 1) & 3)) * 8;

#define STAGE(OPBASE, LS, KT, KH, BUF) do {                                  \
    int _kb = (((KT) & 63) * 64 + (KH) * 32);                                \
    gld_lds16(OPBASE + (size_t)srow0 * IN_F + _kb + scol0,                   \
              LS + ((BUF) * 2 + (KH)) * 16384 + t * 16);                     \
    gld_lds16(OPBASE + (size_t)srow1 * IN_F + _kb + scol1,                   \
              LS + ((BUF) * 2 + (KH)) * 16384 + 8192 + t * 16);              \
} while (0)

    // LDS byte bases for asm ds_read; read slot = quad ^ ((lr>>1)&3)
    const u32 slot16 = (u32)((quad ^ ((lr >> 1) & 3)) * 16);
    const u32 lsA0 = (u32)(size_t)(__attribute__((address_space(3))) char*)lsA;
    const u32 lsB0 = (u32)(size_t)(__attribute__((address_space(3))) char*)lsB;
    const u32 aA = lsA0 + (u32)((wm + lr) * 64) + slot16;
    const u32 aB = lsB0 + (u32)((wn + lr) * 64) + slot16;

    bf16x8 afP0[4], afP1[4], bfE[4];   // kh0 consume set
    bf16x8 afN0[4], afN1[4], bfO[4];   // kh1 consume set
    f32x4 acc[8][4] = {};

// region byte offsets: [buf][kh] x 16 KiB; pm1 adds 4096
#define RA(BUF, KH) (((BUF) * 2 + (KH)) * 16384)
#define RB(BUF, KH) (((BUF) * 2 + (KH)) * 16384)

// inline-asm ds_read_b128 (opaque to waitcnt pass; manual lgkm discipline)
#define DSR(dst, base, OFF) do {                                             \
    u32x4 _r;                                                                \
    asm volatile("ds_read_b128 %0, %1 offset:%2"                             \
                 : "=v"(_r) : "v"(base), "n"(OFF));                          \
    dst = __builtin_bit_cast(bf16x8, _r);                                    \
} while (0)

// one MFMA group: 4 MFMAs, row-tile I of half-tile PM, frag sets AF/BF
#define G4(PM, I, AF, BF) do {                                               \
    _Pragma("unroll")                                                        \
    for (int j = 0; j < 4; ++j)                                              \
        acc[(PM) * 4 + (I)][j] = __builtin_amdgcn_mfma_f32_16x16x32_bf16(    \
            AF[(I)], BF[j], acc[(PM) * 4 + (I)][j], 0, 0, 0);                \
} while (0)

#define FENCE() asm volatile("" ::: "memory")
#define BAR()  do { FENCE(); __builtin_amdgcn_s_barrier(); FENCE(); } while (0)
#define VM4()  asm volatile("s_waitcnt vmcnt(4)" ::: "memory")
#define PRIO(x) __builtin_amdgcn_s_setprio(x)
#define SB()   __builtin_amdgcn_sched_barrier(0)
#define LGKM0SB() do {                                                       \
    asm volatile("s_waitcnt lgkmcnt(0)" ::: "memory"); SB(); } while (0)

// Phase A: consume kh0, inject kh1 sets, stage (t+1).h1 -> buf 1-B
#define PHA(KT, B) do {                                                      \
    STAGE(Abase, lsA, (KT) + 1, 1, 1 - (B));                                 \
    STAGE(Bbase, lsB, (KT) + 1, 1, 1 - (B));                                 \
    LGKM0SB(); PRIO(1);                                                      \
    G4(0,0,afP0,bfE); SB(); DSR(afN0[0], aA, RA(B,1)+0*1024);                \
                            DSR(afN1[0], aA, RA(B,1)+4096+0*1024); SB();     \
    G4(0,1,afP0,bfE); SB(); DSR(afN0[1], aA, RA(B,1)+1*1024);                \
                            DSR(afN1[1], aA, RA(B,1)+4096+1*1024); SB();     \
    G4(0,2,afP0,bfE); SB(); DSR(afN0[2], aA, RA(B,1)+2*1024);                \
                            DSR(afN1[2], aA, RA(B,1)+4096+2*1024); SB();     \
    G4(0,3,afP0,bfE); SB(); DSR(afN0[3], aA, RA(B,1)+3*1024);                \
                            DSR(afN1[3], aA, RA(B,1)+4096+3*1024); SB();     \
    G4(1,0,afP1,bfE); SB(); DSR(bfO[0], aB, RB(B,1)+0*1024);                 \
                            DSR(bfO[1], aB, RB(B,1)+1*1024); SB();           \
    G4(1,1,afP1,bfE); SB(); DSR(bfO[2], aB, RB(B,1)+2*1024);                 \
                            DSR(bfO[3], aB, RB(B,1)+3*1024); SB();           \
    G4(1,2,afP1,bfE);                                                        \
    G4(1,3,afP1,bfE);                                                        \
    PRIO(0); VM4(); BAR();                                                   \
} while (0)

// Phase B: consume kh1, inject next-tile kh0 sets, stage (t+2).h0 -> buf B
#define PHB(KT, B) do {                                                      \
    STAGE(Abase, lsA, (KT) + 2, 0, (B));                                     \
    STAGE(Bbase, lsB, (KT) + 2, 0, (B));                                     \
    LGKM0SB(); PRIO(1);                                                      \
    G4(0,0,afN0,bfO); SB(); DSR(afP0[0], aA, RA(1-(B),0)+0*1024);            \
                            DSR(afP1[0], aA, RA(1-(B),0)+4096+0*1024); SB(); \
    G4(0,1,afN0,bfO); SB(); DSR(afP0[1], aA, RA(1-(B),0)+1*1024);            \
                            DSR(afP1[1], aA, RA(1-(B),0)+4096+1*1024); SB(); \
    G4(0,2,afN0,bfO); SB(); DSR(afP0[2], aA, RA(1-(B),0)+2*1024);            \
                            DSR(afP1[2], aA, RA(1-(B),0)+4096+2*1024); SB(); \
    G4(0,3,afN0,bfO); SB(); DSR(afP0[3], aA, RA(1-(B),0)+3*1024);            \
                            DSR(afP1[3], aA, RA(1-(B),0)+4096+3*1024); SB(); \
    G4(1,0,afN1,bfO); SB(); DSR(bfE[0], aB, RB(1-(B),0)+0*1024);             \
                            DSR(bfE[1], aB, RB(1-(B),0)+1*1024); SB();       \
    G4(1,1,afN1,bfO); SB(); DSR(bfE[2], aB, RB(1-(B),0)+2*1024);             \
                            DSR(bfE[3], aB, RB(1-(B),0)+3*1024); SB();       \
    G4(1,2,afN1,bfO);                                                        \
    G4(1,3,afN1,bfO);                                                        \
    PRIO(0); VM4(); BAR();                                                   \
} while (0)

    // prologue: t0.h0, t0.h1 (buf0), t1.h0 (buf1) = 12 loads
    STAGE(Abase, lsA, 0, 0, 0);
    STAGE(Bbase, lsB, 0, 0, 0);
    STAGE(Abase, lsA, 0, 1, 0);
    STAGE(Bbase, lsB, 0, 1, 0);
    STAGE(Abase, lsA, 1, 0, 1);
    STAGE(Bbase, lsB, 1, 0, 1);
    VM4();   // retires t0.h0 + t0.h1 for this wave (t1.h0 stays in flight)
    BAR();
    // preload kh0 consume set (buf0): afP0=pm0, afP1=pm1, bfE
    DSR(bfE[0], aB, RB(0,0)+0*1024); DSR(bfE[1], aB, RB(0,0)+1*1024);
    DSR(bfE[2], aB, RB(0,0)+2*1024); DSR(bfE[3], aB, RB(0,0)+3*1024);
    DSR(afP0[0], aA, RA(0,0)+0*1024); DSR(afP0[1], aA, RA(0,0)+1*1024);
    DSR(afP0[2], aA, RA(0,0)+2*1024); DSR(afP0[3], aA, RA(0,0)+3*1024);
    DSR(afP1[0], aA, RA(0,0)+4096+0*1024); DSR(afP1[1], aA, RA(0,0)+4096+1*1024);
    DSR(afP1[2], aA, RA(0,0)+4096+2*1024); DSR(afP1[3], aA, RA(0,0)+4096+3*1024);

    for (int kt = 0; kt < 64; kt += 2) {
        PHA(kt, 0); PHB(kt, 0);
        PHA(kt + 1, 1); PHB(kt + 1, 1);
    }

    asm volatile("s_waitcnt vmcnt(0) lgkmcnt(0)" ::: "memory");

    // epilogue: C/D layout col = lane&15, row = (lane>>4)*4 + reg
    const int row0 = bm * 256 + wm + quad * 4;
    const int col0 = bn * 256 + wn + lr;
#pragma unroll
    for (int j = 0; j < 4; ++j) {
        const int col = col0 + j * 16;
        const float bv = bias[col];
#pragma unroll
        for (int i = 0; i < 8; ++i) {
            const int row = row0 + i * 16;
#pragma unroll
            for (int r = 0; r < 4; ++r)
                C[(size_t)(row + r) * OUT_F + col] = acc[i][j][r] + bv;
        }
    }
}

extern "C" void kernel_launch(void* const* d_in, const int* in_sizes, int n_in,
                              void* d_out, int out_size, void* d_ws, size_t ws_size,
                              hipStream_t stream) {
    (void)in_sizes; (void)n_in; (void)out_size; (void)ws_size;
    const float* x       = (const float*)d_in[0];
    const u32*   qweight = (const u32*)d_in[1];
    const u32*   qzeros  = (const u32*)d_in[2];
    const float* scales  = (const float*)d_in[3];
    const float* bias    = (const float*)d_in[4];
    float* out = (float*)d_out;

    __bf16* W   = (__bf16*)d_ws;                                     // 32 MB
    __bf16* Abf = (__bf16*)((char*)d_ws + (size_t)OUT_F * IN_F * 2); // 32 MB

    prep_kernel<<<dim3(DEQ_BLOCKS + CVT_BLOCKS), dim3(256), 0, stream>>>(
        qweight, qzeros, scales, x, W, Abf);
    gemm2p<<<dim3(256), dim3(512), 0, stream>>>(Abf, W, bias, out);
}